// Round 19
// baseline (336.559 us; speedup 1.0000x reference)
//
#include <hip/hip_runtime.h>

typedef __bf16 bf16x8_t __attribute__((ext_vector_type(8)));
typedef float f32x4 __attribute__((ext_vector_type(4)));
typedef unsigned short u16x8 __attribute__((ext_vector_type(8)));
typedef unsigned short u16x4 __attribute__((ext_vector_type(4)));

#define EPS 1e-5f

__device__ __forceinline__ unsigned short f2bf(float f) {
    unsigned u = __builtin_bit_cast(unsigned, f);
    u += 0x7fff + ((u >> 16) & 1);          // RTNE
    return (unsigned short)(u >> 16);
}

// direct global->LDS 16B (dwordx4). LDS dest: wave-uniform base + lane*16.
__device__ __forceinline__ void gload16(const unsigned short* g, unsigned short* l) {
    __builtin_amdgcn_global_load_lds(
        (const __attribute__((address_space(1))) unsigned int*)g,
        (__attribute__((address_space(3))) unsigned int*)l,
        16, 0, 0);
}

// counted vmcnt wait (compile-time N)
template <int N> __device__ __forceinline__ void s_waitcnt_vm() {
    if constexpr (N == 0)       asm volatile("s_waitcnt vmcnt(0)" ::: "memory");
    else if constexpr (N == 4)  asm volatile("s_waitcnt vmcnt(4)" ::: "memory");
    else if constexpr (N == 5)  asm volatile("s_waitcnt vmcnt(5)" ::: "memory");
    else if constexpr (N == 8)  asm volatile("s_waitcnt vmcnt(8)" ::: "memory");
    else if constexpr (N == 12) asm volatile("s_waitcnt vmcnt(12)" ::: "memory");
    else static_assert(N == 0, "unsupported vmcnt");
}

// ------- fused prep: one launch does nhwc convert + weight repack + BN fold + pad rings -------
__device__ __forceinline__ void wconv3x3(const float* __restrict__ w, unsigned short* __restrict__ dst,
                                         int Cout, int Kp, int CIN, int CINP, int idx) {
    int m = idx / Kp, k = idx - m * Kp;
    int tap = k / CINP, ic = k - tap * CINP;
    unsigned short v = 0;
    if (m < Cout && tap < 9 && ic < CIN) {
        int kh = tap / 3, kw = tap - kh * 3;
        v = f2bf(w[((m * CIN + ic) * 3 + kh) * 3 + kw]);
    }
    dst[idx] = v;
}

__device__ __forceinline__ void ring1_zero(unsigned short* __restrict__ buf, int Hp, int Wp,
                                           int C8, int imgStrideElems, int nimg, int idx) {
    int nb = 2 * Wp + 2 * (Hp - 2);
    int per = nb * C8;
    if (idx >= per * nimg) return;
    int z = idx / per, q = idx - z * per;
    int p = q / C8, cc = q - p * C8;
    int row, col;
    if (p < Wp) { row = 0; col = p; }
    else if (p < 2 * Wp) { row = Hp - 1; col = p - Wp; }
    else { int e = p - 2 * Wp; row = 1 + (e >> 1); col = (e & 1) ? Wp - 1 : 0; }
    const u16x8 zv = {0, 0, 0, 0, 0, 0, 0, 0};
    *(u16x8*)&buf[(size_t)z * imgStrideElems + ((size_t)row * Wp + col) * (C8 * 8) + cc * 8] = zv;
}

__global__ void prep_all(const float* __restrict__ cloth, const float* __restrict__ person,
                         const float* __restrict__ w1, const float* __restrict__ w2,
                         const float* __restrict__ w3, const float* __restrict__ fw1,
                         const float* __restrict__ fw2, const float* __restrict__ fw3,
                         const float* __restrict__ b1, const float* __restrict__ g1,
                         const float* __restrict__ be1, const float* __restrict__ m1,
                         const float* __restrict__ v1,
                         const float* __restrict__ b2, const float* __restrict__ g2,
                         const float* __restrict__ be2, const float* __restrict__ m2,
                         const float* __restrict__ v2,
                         const float* __restrict__ b3, const float* __restrict__ g3,
                         const float* __restrict__ be3, const float* __restrict__ m3,
                         const float* __restrict__ v3,
                         const float* __restrict__ fb1, const float* __restrict__ fb2,
                         const float* __restrict__ fb3,
                         unsigned short* nhwc, unsigned short* t1, unsigned short* t2,
                         unsigned short* corr, unsigned short* f1b, unsigned short* f2b,
                         unsigned short* d1, unsigned short* d2, unsigned short* d3,
                         unsigned short* d4, unsigned short* d5, unsigned short* d6,
                         float* __restrict__ aff) {
    int b = blockIdx.x;
    int tid = threadIdx.x;
    if (b < 16384) {
        // nhwc convert: NCHW fp32 [3][512][512] -> padded NHWC4 bf16 [518][518][4]
        int z = b >> 10;
        const float* src = (z < 8) ? cloth + (size_t)z * 786432
                                   : person + (size_t)(z - 8) * 786432;
        int p = (b & 1023) * 256 + tid;
        int row = p >> 9, col = p & 511;
        u16x4 o;
        o[0] = f2bf(src[p]);
        o[1] = f2bf(src[262144 + p]);
        o[2] = f2bf(src[524288 + p]);
        o[3] = 0;
        *(u16x4*)&nhwc[(size_t)z * 1073296 + ((size_t)(row + 3) * 518 + col + 3) * 4] = o;
    } else if (b < 18900) {
        // weight repack + BN fold (flattened)
        int idx = (b - 16384) * 256 + tid;
        if (idx < 16384) {        // conv1: [64,3,7,7] -> [64][256], k = kh*32 + kw*4 + ic
            int m = idx >> 8, k = idx & 255;
            int kh = k >> 5, r = k & 31, kw = r >> 2, ic = r & 3;
            unsigned short v = 0;
            if (kh < 7 && kw < 7 && ic < 3) v = f2bf(w1[((m * 3 + ic) * 7 + kh) * 7 + kw]);
            d1[idx] = v;
        } else if (idx < 90112)  wconv3x3(w2, d2, 128, 576, 64, 64, idx - 16384);
        else if (idx < 385024)   wconv3x3(w3, d3, 256, 1152, 128, 128, idx - 90112);
        else if (idx < 532480)   wconv3x3(fw1, d4, 128, 1152, 81, 128, idx - 385024);
        else if (idx < 606208)   wconv3x3(fw2, d5, 64, 1152, 128, 128, idx - 532480);
        else if (idx < 643072)   wconv3x3(fw3, d6, 2, 576, 64, 64, idx - 606208);
        else {                   // BN fold (642 channels)
            int i = idx - 643072;
            if (i < 64) {
                float s = g1[i] * rsqrtf(v1[i] + EPS);
                aff[i] = s; aff[64 + i] = (b1[i] - m1[i]) * s + be1[i];
            } else if (i < 192) {
                int c = i - 64; float s = g2[c] * rsqrtf(v2[c] + EPS);
                aff[128 + c] = s; aff[256 + c] = (b2[c] - m2[c]) * s + be2[c];
            } else if (i < 448) {
                int c = i - 192; float s = g3[c] * rsqrtf(v3[c] + EPS);
                aff[384 + c] = s; aff[640 + c] = (b3[c] - m3[c]) * s + be3[c];
            } else if (i < 576) {
                int c = i - 448; aff[896 + c] = 1.f; aff[1024 + c] = fb1[c];
            } else if (i < 640) {
                int c = i - 576; aff[1152 + c] = 1.f; aff[1216 + c] = fb2[c];
            } else if (i < 642) {
                int c = i - 640; aff[1280 + c] = 1.f; aff[1288 + c] = fb3[c];
            }
        }
    } else {
        // pad rings: role 0 nhwc 3-ring, 1 t1, 2 t2, 3 corr/f1b/f2b
        int bb = b - 18900;
        int role = bb / 516;
        int idx = (bb - role * 516) * 256 + tid;
        if (role == 0) {
            if (idx >= 16 * 6180) return;
            int z = idx / 6180, p = idx - z * 6180;
            int r, c;
            if (p < 1554) { r = p / 518; c = p - (p / 518) * 518; }
            else if (p < 3108) { int q = p - 1554; r = 515 + q / 518; c = q - (q / 518) * 518; }
            else { int q = p - 3108; r = 3 + q / 6; int k = q - (q / 6) * 6; c = (k < 3) ? k : 512 + k; }
            const u16x4 zv = {0, 0, 0, 0};
            *(u16x4*)&nhwc[(size_t)z * 1073296 + ((size_t)r * 518 + c) * 4] = zv;
        } else if (role == 1) {
            ring1_zero(t1, 258, 258, 8, 4260096, 16, idx);
        } else if (role == 2) {
            ring1_zero(t2, 130, 130, 16, 2163200, 16, idx);
        } else {
            if (idx < 33280) ring1_zero(corr, 66, 66, 16, 557568, 8, idx);
            else if (idx < 66560) ring1_zero(f1b, 66, 66, 16, 557568, 8, idx - 33280);
            else if (idx < 83200) ring1_zero(f2b, 66, 66, 8, 278784, 8, idx - 66560);
        }
    }
}

// ------- MFMA GEMM, implicit im2col, global_load_lds staging -------
// MODE 1: 3x3 conv pad1, X = padded NHWC [HIN+2][HIN+2][CIN], K layout tap*CIN+ic. KSTEP=64.
// MODE 2: conv1 7x7 s2 p3, KSTEP=32: one kh row per round (NKT=7, zero kh=7 skipped).
// PIPE 0: single LDS buffer.  PIPE 1: dbuf + counted vmcnt.
// WREG 1 (MODE1/KSTEP64 only): W-fragments loaded straight from L2 into registers each
// round (W panel is small + L2-resident); W leaves LDS -> ~half LDS, 2x blocks/CU.
// W reg loads are issued BEFORE the X gload_lds batch, so vmcnt(SXC) certifies both.
template <int WR, int WS, int MODE, bool RELU, bool OUT_NCHW, int CIN, int NKT,
          int HIN, int WOS, int STRIDE, int OPAD, int PIPE, int KSTEP, int WREG>
__global__ __launch_bounds__(WR * WS * 64)
void gemm_conv(const unsigned short* __restrict__ X, const unsigned short* __restrict__ Wmk,
               const float* __restrict__ scale, const float* __restrict__ shift,
               void* __restrict__ Yv, int Cout, int xImgStride, int yImgStride) {
    constexpr int BR = WR * 64, BS = WS * 64, NT = WR * WS * 64;
    constexpr int CPR_K = KSTEP / 8;                      // 16B chunks per LDS row
    constexpr int SXC = BR * CPR_K / NT, SWC = BS * CPR_K / NT;
    constexpr int NLOAD = WREG ? SXC : (SXC + SWC);
    constexpr int KP = (MODE == 1) ? NKT * KSTEP : 256;   // weight row stride
    constexpr int WP = HIN + ((MODE == 2) ? 6 : 2);       // padded width
    constexpr int WOUT = 1 << WOS;
    constexpr int WOP = WOUT + 2 * OPAD;
    constexpr int NBUF = PIPE ? 2 : 1;
    constexpr int EPS_LDK = BS + 8;                        // epilogue row stride
    constexpr int GEMM_ELEMS = NBUF * BR * KSTEP + (WREG ? 0 : NBUF * BS * KSTEP);
    constexpr int EPI_ELEMS = BR * EPS_LDK;
    constexpr int LDS_ELEMS = GEMM_ELEMS > EPI_ELEMS ? GEMM_ELEMS : EPI_ELEMS;
    __shared__ __align__(16) unsigned short lds[LDS_ELEMS];
    unsigned short* XsB = lds;                       // [NBUF][BR*KSTEP]
    unsigned short* WsB = lds + NBUF * BR * KSTEP;   // [NBUF][BS*KSTEP] (unused if WREG)
    const int tid = threadIdx.x;
    const int lane = tid & 63, wid = tid >> 6;
    const int wr = wid % WR, wsx = wid / WR;
    int bx = blockIdx.x;
    { const int nx = gridDim.x; bx = (bx & 7) * (nx >> 3) + (bx >> 3); }  // XCD swizzle
    const int r0 = bx * BR, s0 = blockIdx.y * BS;
    const int z = blockIdx.z;
    const int lr = lane & 15, lk = lane >> 4;
    const unsigned short* Ximg = X + (size_t)z * xImgStride;

    // per-chunk global source base (kt=0); LDS slot p of row r holds K-chunk p^(r&(CPR_K-1))
    const unsigned short* xsrc[SXC];
    #pragma unroll
    for (int i = 0; i < SXC; ++i) {
        int c = i * NT + tid;
        int row = c / CPR_K, chs = (c % CPR_K) ^ (row & (CPR_K - 1));
        int r = r0 + row;
        int oh = r >> WOS, ow = r & (WOUT - 1);
        if (MODE == 1)
            xsrc[i] = Ximg + ((size_t)(oh * STRIDE) * WP + (size_t)(ow * STRIDE)) * CIN + chs * 8;
        else if (KSTEP == 64)
            xsrc[i] = Ximg + ((size_t)(2 * oh + (chs >> 2)) * WP + 2 * ow + (chs & 3) * 2) * 4;
        else  // MODE 2, KSTEP 32: chunk = kw pair, one kh row per round
            xsrc[i] = Ximg + ((size_t)(2 * oh) * WP + 2 * ow + chs * 2) * 4;
    }
    // W sources: LDS path (per-chunk) or register path (per-fragment)
    const unsigned short* wsrc[SWC];
    const unsigned short* wfrag[4];
    #pragma unroll
    for (int i = 0; i < SWC; ++i) {
        int c = i * NT + tid;
        int row = c / CPR_K, chs = (c % CPR_K) ^ (row & (CPR_K - 1));
        wsrc[i] = Wmk + (size_t)(s0 + row) * KP + chs * 8;
    }
    #pragma unroll
    for (int si = 0; si < 4; ++si)
        wfrag[si] = Wmk + (size_t)(s0 + wsx * 64 + si * 16 + lr) * KP + lk * 8;

    // fragment row bases
    int arow[4], brow[4];
    #pragma unroll
    for (int mi = 0; mi < 4; ++mi) arow[mi] = (wr * 64 + mi * 16 + lr) * KSTEP;
    #pragma unroll
    for (int si = 0; si < 4; ++si) brow[si] = (wsx * 64 + si * 16 + lr) * KSTEP;

    const f32x4 fz = {0.f, 0.f, 0.f, 0.f};
    f32x4 acc[4][4];
    #pragma unroll
    for (int a = 0; a < 4; ++a)
        #pragma unroll
        for (int b = 0; b < 4; ++b) acc[a][b] = fz;

    // stage X (and W if not WREG) for round kt into LDS buffer b
    auto stage = [&](int kt, int b) {
        size_t koff;
        if (MODE == 1) {
            const int tap = (kt * KSTEP) / CIN;
            const int kh = tap / 3, kw = tap - (tap / 3) * 3;
            const int icb0 = (kt * KSTEP) % CIN;
            koff = ((size_t)kh * WP + kw) * CIN + icb0;
        } else if (KSTEP == 64) {
            koff = (size_t)kt * 2 * WP * 4;
        } else {
            koff = (size_t)kt * WP * 4;
        }
        #pragma unroll
        for (int i = 0; i < SXC; ++i)
            gload16(xsrc[i] + koff, &XsB[b * BR * KSTEP + (i * NT + wid * 64) * 8]);
        if constexpr (!WREG) {
            #pragma unroll
            for (int i = 0; i < SWC; ++i)
                gload16(wsrc[i] + (size_t)kt * KSTEP, &WsB[b * BS * KSTEP + (i * NT + wid * 64) * 8]);
        }
    };
    // MFMA over buffer b; wv = register B-fragments (WREG path)
    auto compute = [&](int b, u16x8 wv[2][4]) {
        if constexpr (KSTEP == 64) {
            #pragma unroll
            for (int hf = 0; hf < 2; ++hf) {
                const int cA = (((hf * 4 + lk) ^ (lr & 7)) * 8);
                u16x8 af[4], bfr[4];
                #pragma unroll
                for (int mi = 0; mi < 4; ++mi) af[mi] = *(const u16x8*)&XsB[b * BR * 64 + arow[mi] + cA];
                #pragma unroll
                for (int si = 0; si < 4; ++si)
                    bfr[si] = WREG ? wv[hf][si] : *(const u16x8*)&WsB[b * BS * 64 + brow[si] + cA];
                #pragma unroll
                for (int mi = 0; mi < 4; ++mi)
                    #pragma unroll
                    for (int si = 0; si < 4; ++si)
                        acc[mi][si] = __builtin_amdgcn_mfma_f32_16x16x32_bf16(
                            __builtin_bit_cast(bf16x8_t, af[mi]),
                            __builtin_bit_cast(bf16x8_t, bfr[si]), acc[mi][si], 0, 0, 0);
            }
        } else {
            const int cA = ((lk ^ (lr & 3)) * 8);
            u16x8 af[4], bfr[4];
            #pragma unroll
            for (int mi = 0; mi < 4; ++mi) af[mi] = *(const u16x8*)&XsB[b * BR * 32 + arow[mi] + cA];
            #pragma unroll
            for (int si = 0; si < 4; ++si) bfr[si] = *(const u16x8*)&WsB[b * BS * 32 + brow[si] + cA];
            #pragma unroll
            for (int mi = 0; mi < 4; ++mi)
                #pragma unroll
                for (int si = 0; si < 4; ++si)
                    acc[mi][si] = __builtin_amdgcn_mfma_f32_16x16x32_bf16(
                        __builtin_bit_cast(bf16x8_t, af[mi]),
                        __builtin_bit_cast(bf16x8_t, bfr[si]), acc[mi][si], 0, 0, 0);
        }
    };

    if (PIPE == 0) {
        #pragma unroll
        for (int kt = 0; kt < NKT; ++kt) {
            stage(kt, 0);
            __syncthreads();
            u16x8 wv[2][4];
            compute(0, wv);
            __syncthreads();
        }
    } else {
        stage(0, 0);
        #pragma unroll
        for (int kt = 0; kt < NKT; ++kt) {
            const int cur = kt & 1;
            u16x8 wv[2][4];
            if constexpr (WREG) {
                // W reg loads FIRST (older in VMEM queue than the X gloads below)
                #pragma unroll
                for (int hf = 0; hf < 2; ++hf)
                    #pragma unroll
                    for (int si = 0; si < 4; ++si)
                        wv[hf][si] = *(const u16x8*)(wfrag[si] + (size_t)kt * KSTEP + hf * 32);
            }
            if (kt + 1 < NKT) {
                stage(kt + 1, cur ^ 1);
                s_waitcnt_vm<NLOAD>();   // prev X loads + this round's W regs landed
            } else {
                s_waitcnt_vm<0>();
            }
            __builtin_amdgcn_sched_barrier(0);
            __builtin_amdgcn_s_barrier();
            __builtin_amdgcn_sched_barrier(0);
            compute(cur, wv);
            __builtin_amdgcn_sched_barrier(0);
            __builtin_amdgcn_s_barrier();   // reads of buf[cur] done before restage
        }
    }

    // ---- epilogue ----
    if (OUT_NCHW) {
        // fconv3: scalar fp32 NCHW stores (tiny)
        #pragma unroll
        for (int si = 0; si < 4; ++si) {
            int col = s0 + wsx * 64 + si * 16 + lr;
            bool cok = col < Cout;
            float sc = cok ? scale[col] : 0.f;
            float sh = cok ? shift[col] : 0.f;
            #pragma unroll
            for (int mi = 0; mi < 4; ++mi) {
                int rbase = r0 + wr * 64 + mi * 16 + lk * 4;
                #pragma unroll
                for (int j = 0; j < 4; ++j) {
                    float v = acc[mi][si][j] * sc + sh;
                    if (RELU) v = fmaxf(v, 0.f);
                    if (cok) ((float*)Yv)[(size_t)z * yImgStride + col * 4096 + rbase + j] = v;
                }
            }
        }
    } else {
        // stage bf16 tile in LDS (stride BS+8), then coalesced u16x8 stores
        __syncthreads();
        unsigned short* epi = lds;
        #pragma unroll
        for (int si = 0; si < 4; ++si) {
            int col = wsx * 64 + si * 16 + lr;
            float sc = scale[s0 + col];
            float sh = shift[s0 + col];
            #pragma unroll
            for (int mi = 0; mi < 4; ++mi) {
                int rowl = wr * 64 + mi * 16 + lk * 4;
                #pragma unroll
                for (int j = 0; j < 4; ++j) {
                    float v = acc[mi][si][j] * sc + sh;
                    if (RELU) v = fmaxf(v, 0.f);
                    epi[(rowl + j) * EPS_LDK + col] = f2bf(v);
                }
            }
        }
        __syncthreads();
        constexpr int NCH = BR * BS / 8 / NT;        // 8-col chunks per thread
        constexpr int CPR = BS / 8;                  // chunks per row
        #pragma unroll
        for (int i = 0; i < NCH; ++i) {
            int c = i * NT + tid;
            int row = c / CPR, colc = c - (c / CPR) * CPR;
            int r = r0 + row;
            int oh = r >> WOS, ow = r & (WOUT - 1);
            size_t off = ((size_t)(oh + OPAD) * WOP + ow + OPAD) * Cout + s0 + colc * 8;
            *(u16x8*)((unsigned short*)Yv + (size_t)z * yImgStride + off) =
                *(const u16x8*)&epi[row * EPS_LDK + colc * 8];
        }
    }
}

// ------- banded-MFMA 81-shift correlation, di split across grid for occupancy -------
__global__ __launch_bounds__(256)
void corr_mfma(const unsigned short* __restrict__ cf,
               const unsigned short* __restrict__ pf,
               unsigned short* __restrict__ out) {
    const int h = blockIdx.x;            // 0..63
    const int di = (int)blockIdx.y - 4;  // -4..4
    const int z = blockIdx.z;            // 0..7
    const int tid = threadIdx.x;
    const int lane = tid & 63, t = tid >> 6;
    const int lr = lane & 15, lk = lane >> 4;
    const unsigned short* cfi = cf + (size_t)z * 1048576;
    const unsigned short* pfi = pf + (size_t)z * 1048576;
    unsigned short* outp = out + (size_t)z * 557568;

    u16x8 a[8];
    {
        const unsigned short* ap = cfi + ((size_t)(h * 64 + t * 16 + lr)) * 256 + lk * 8;
        #pragma unroll
        for (int ks = 0; ks < 8; ++ks) a[ks] = *(const u16x8*)(ap + ks * 32);
    }

    const u16x8 zz = {0, 0, 0, 0, 0, 0, 0, 0};
    const int h2 = h + di;
    const bool hok = (unsigned)h2 < 64u;
    #pragma unroll
    for (int ct = 0; ct < 2; ++ct) {
        const int wpg = t * 16 - 8 + ct * 16 + lr;
        u16x8 b[8];
        if (hok && (unsigned)wpg < 64u) {
            const unsigned short* bp = pfi + ((size_t)(h2 * 64 + wpg)) * 256 + lk * 8;
            #pragma unroll
            for (int ks = 0; ks < 8; ++ks) b[ks] = *(const u16x8*)(bp + ks * 32);
        } else {
            #pragma unroll
            for (int ks = 0; ks < 8; ++ks) b[ks] = zz;
        }
        f32x4 acc0 = {0.f, 0.f, 0.f, 0.f}, acc1 = {0.f, 0.f, 0.f, 0.f};
        #pragma unroll
        for (int ks = 0; ks < 8; ks += 2) {
            acc0 = __builtin_amdgcn_mfma_f32_16x16x32_bf16(
                __builtin_bit_cast(bf16x8_t, a[ks]),
                __builtin_bit_cast(bf16x8_t, b[ks]), acc0, 0, 0, 0);
            acc1 = __builtin_amdgcn_mfma_f32_16x16x32_bf16(
                __builtin_bit_cast(bf16x8_t, a[ks + 1]),
                __builtin_bit_cast(bf16x8_t, b[ks + 1]), acc1, 0, 0, 0);
        }
        const int wl = lk * 4;
        const int wpl = ct * 16 - 8 + lr;
        #pragma unroll
        for (int j = 0; j < 4; ++j) {
            int dj = wpl - (wl + j);
            if (dj >= -4 && dj <= 4) {
                int s = (di + 4) * 9 + dj + 4;
                int w = t * 16 + wl + j;
                outp[((size_t)(h + 1) * 66 + w + 1) * 128 + s] =
                    f2bf(acc0[j] + acc1[j]);
            }
        }
    }
}

// ---------------- launch ----------------
extern "C" void kernel_launch(void* const* d_in, const int* in_sizes, int n_in,
                              void* d_out, int out_size, void* d_ws, size_t ws_size,
                              hipStream_t stream) {
    const float* cloth  = (const float*)d_in[0];
    const float* person = (const float*)d_in[1];
    const float* w1 = (const float*)d_in[2];  const float* b1 = (const float*)d_in[3];
    const float* g1 = (const float*)d_in[4];  const float* be1 = (const float*)d_in[5];
    const float* m1 = (const float*)d_in[6];  const float* v1 = (const float*)d_in[7];
    const float* w2 = (const float*)d_in[8];  const float* b2 = (const float*)d_in[9];
    const float* g2 = (const float*)d_in[10]; const float* be2 = (const float*)d_in[11];
    const float* m2 = (const float*)d_in[12]; const float* v2 = (const float*)d_in[13];
    const float* w3 = (const float*)d_in[14]; const float* b3 = (const float*)d_in[15];
    const float* g3 = (const float*)d_in[16]; const float* be3 = (const float*)d_in[17];
    const float* m3 = (const float*)d_in[18]; const float* v3 = (const float*)d_in[19];
    const float* fw1 = (const float*)d_in[20]; const float* fb1 = (const float*)d_in[21];
    const float* fw2 = (const float*)d_in[22]; const float* fb2 = (const float*)d_in[23];
    const float* fw3 = (const float*)d_in[24]; const float* fb3 = (const float*)d_in[25];

    char* ws = (char*)d_ws;
    auto U = [&](size_t off) { return (unsigned short*)(ws + off); };
    // ---- layout (bytes), ws_size = 256 MiB = 268,435,456 ----
    unsigned short* nhwc = U(0);             // [518][518][4] x16 = 34,345,472
    unsigned short* t1   = U(34345472);      // [258][258][64] x16 = 136,323,072 -> ends 170,668,544
    unsigned short* cf   = U(34345472);      // alias t1 (dead after conv2): [64][64][256] x16
    unsigned short* t2   = U(170668544);     // [130][130][128] x16 = 69,222,400 -> ends 239,890,944
    unsigned short* w1mk  = U(239890944);    //  32,768 (64x256)
    unsigned short* w2mk  = U(239923712);    // 147,456 (128x576)
    unsigned short* w3mk  = U(240071168);    // 589,824 (256x1152)
    unsigned short* fw1mk = U(240660992);    // 294,912 (128x1152)
    unsigned short* fw2mk = U(240955904);    // 147,456 (64x1152)
    unsigned short* fw3mk = U(241103360);    //  73,728 (64x576) -> ends 241,177,088
    float* aff = (float*)(ws + 241177088);   // 8 KB
    unsigned short* corr = U(241185280);     // [66][66][128] x8 = 8,921,088 -> ends 250,106,368
    unsigned short* f1b  = U(250106368);     // [66][66][128] x8 = 8,921,088 -> ends 259,027,456
    unsigned short* f2b  = U(259027456);     // [66][66][64]  x8 = 4,460,544 -> ends 263,488,000
    float *s1 = aff,         *sh1 = aff + 64,   *s2 = aff + 128,  *sh2 = aff + 256;
    float *s3 = aff + 384,   *sh3 = aff + 640,  *sf1 = aff + 896, *shf1 = aff + 1024;
    float *sf2 = aff + 1152, *shf2 = aff + 1216, *sf3 = aff + 1280, *shf3 = aff + 1288;

    // single fused prep launch: nhwc convert (16384 blk) + weights/affine (2516) + rings (2064)
    prep_all<<<20964, 256, 0, stream>>>(cloth, person, w1, w2, w3, fw1, fw2, fw3,
                                        b1, g1, be1, m1, v1, b2, g2, be2, m2, v2,
                                        b3, g3, be3, m3, v3, fb1, fb2, fb3,
                                        nhwc, t1, t2, corr, f1b, f2b,
                                        w1mk, w2mk, w3mk, fw1mk, fw2mk, fw3mk, aff);

    // conv1: 7x7 s2 p3, nhwc[518,518,4] -> t1 pad[258,258,64]  (dbuf BK32 NKT7, R18-proven)
    gemm_conv<4, 1, 2, true, false, 4, 7, 512, 8, 2, 1, 1, 32, 0><<<dim3(256, 1, 16), 256, 0, stream>>>(
        nhwc, w1mk, s1, sh1, t1, 64, 1073296, 4260096);
    // conv2: 3x3 s2 p1, t1 -> t2 pad[130,130,128]   (dbuf BK64, W-in-regs: 34.8KB LDS)
    gemm_conv<2, 2, 1, true, false, 64, 9, 256, 7, 2, 1, 1, 64, 1><<<dim3(128, 1, 16), 256, 0, stream>>>(
        t1, w2mk, s2, sh2, t2, 128, 4260096, 2163200);
    // conv3: 3x3 s2 p1, t2 -> cf/pf unpadded [64,64,256]   (dbuf BK64, W-in-regs)
    gemm_conv<2, 2, 1, true, false, 128, 18, 128, 6, 2, 0, 1, 64, 1><<<dim3(32, 2, 16), 256, 0, stream>>>(
        t2, w3mk, s3, sh3, cf, 256, 2163200, 1048576);

    // correlation (banded MFMA, di-split grid) -> corr pad[66,66,128]
    corr_mfma<<<dim3(64, 9, 8), 256, 0, stream>>>(cf, cf + (size_t)8 * 1048576, corr);

    // fconv1: 3x3 p1, corr -> f1b pad[66,66,128]   (dbuf BK64, BR=64 tile, W-in-regs)
    gemm_conv<1, 2, 1, true, false, 128, 18, 64, 6, 1, 1, 1, 64, 1><<<dim3(64, 1, 8), 128, 0, stream>>>(
        corr, fw1mk, sf1, shf1, f1b, 128, 557568, 557568);
    // fconv2: 3x3 p1, f1b -> f2b pad[66,66,64]   (dbuf BK64, frozen)
    gemm_conv<2, 1, 1, true, false, 128, 18, 64, 6, 1, 1, 1, 64, 0><<<dim3(32, 1, 8), 128, 0, stream>>>(
        f1b, fw2mk, sf2, shf2, f2b, 64, 557568, 278784);
    // fconv3: 3x3 p1, f2b -> d_out NCHW fp32 [8][2][64][64]   (dbuf BK64, frozen)
    gemm_conv<2, 1, 1, false, true, 64, 9, 64, 6, 1, 0, 1, 64, 0><<<dim3(32, 1, 8), 128, 0, stream>>>(
        f2b, fw3mk, sf3, shf3, (float*)d_out, 2, 278784, 8192);
}

// Round 20
// 258.033 us; speedup vs baseline: 1.3043x; 1.3043x over previous
//
#include <hip/hip_runtime.h>

typedef __bf16 bf16x8_t __attribute__((ext_vector_type(8)));
typedef float f32x4 __attribute__((ext_vector_type(4)));
typedef unsigned short u16x8 __attribute__((ext_vector_type(8)));
typedef unsigned short u16x4 __attribute__((ext_vector_type(4)));

#define EPS 1e-5f

__device__ __forceinline__ unsigned short f2bf(float f) {
    unsigned u = __builtin_bit_cast(unsigned, f);
    u += 0x7fff + ((u >> 16) & 1);          // RTNE
    return (unsigned short)(u >> 16);
}

// direct global->LDS 16B (dwordx4). LDS dest: wave-uniform base + lane*16.
__device__ __forceinline__ void gload16(const unsigned short* g, unsigned short* l) {
    __builtin_amdgcn_global_load_lds(
        (const __attribute__((address_space(1))) unsigned int*)g,
        (__attribute__((address_space(3))) unsigned int*)l,
        16, 0, 0);
}

// counted vmcnt wait (compile-time N)
template <int N> __device__ __forceinline__ void s_waitcnt_vm() {
    if constexpr (N == 0)       asm volatile("s_waitcnt vmcnt(0)" ::: "memory");
    else if constexpr (N == 5)  asm volatile("s_waitcnt vmcnt(5)" ::: "memory");
    else if constexpr (N == 8)  asm volatile("s_waitcnt vmcnt(8)" ::: "memory");
    else if constexpr (N == 10) asm volatile("s_waitcnt vmcnt(10)" ::: "memory");
    else if constexpr (N == 12) asm volatile("s_waitcnt vmcnt(12)" ::: "memory");
    else static_assert(N == 0, "unsupported vmcnt");
}

// ------- fused prep: one launch does nhwc convert + weight repack + BN fold + pad rings -------
__device__ __forceinline__ void wconv3x3(const float* __restrict__ w, unsigned short* __restrict__ dst,
                                         int Cout, int Kp, int CIN, int CINP, int idx) {
    int m = idx / Kp, k = idx - m * Kp;
    int tap = k / CINP, ic = k - tap * CINP;
    unsigned short v = 0;
    if (m < Cout && tap < 9 && ic < CIN) {
        int kh = tap / 3, kw = tap - kh * 3;
        v = f2bf(w[((m * CIN + ic) * 3 + kh) * 3 + kw]);
    }
    dst[idx] = v;
}

__device__ __forceinline__ void ring1_zero(unsigned short* __restrict__ buf, int Hp, int Wp,
                                           int C8, int imgStrideElems, int nimg, int idx) {
    int nb = 2 * Wp + 2 * (Hp - 2);
    int per = nb * C8;
    if (idx >= per * nimg) return;
    int z = idx / per, q = idx - z * per;
    int p = q / C8, cc = q - p * C8;
    int row, col;
    if (p < Wp) { row = 0; col = p; }
    else if (p < 2 * Wp) { row = Hp - 1; col = p - Wp; }
    else { int e = p - 2 * Wp; row = 1 + (e >> 1); col = (e & 1) ? Wp - 1 : 0; }
    const u16x8 zv = {0, 0, 0, 0, 0, 0, 0, 0};
    *(u16x8*)&buf[(size_t)z * imgStrideElems + ((size_t)row * Wp + col) * (C8 * 8) + cc * 8] = zv;
}

__global__ void prep_all(const float* __restrict__ cloth, const float* __restrict__ person,
                         const float* __restrict__ w1, const float* __restrict__ w2,
                         const float* __restrict__ w3, const float* __restrict__ fw1,
                         const float* __restrict__ fw2, const float* __restrict__ fw3,
                         const float* __restrict__ b1, const float* __restrict__ g1,
                         const float* __restrict__ be1, const float* __restrict__ m1,
                         const float* __restrict__ v1,
                         const float* __restrict__ b2, const float* __restrict__ g2,
                         const float* __restrict__ be2, const float* __restrict__ m2,
                         const float* __restrict__ v2,
                         const float* __restrict__ b3, const float* __restrict__ g3,
                         const float* __restrict__ be3, const float* __restrict__ m3,
                         const float* __restrict__ v3,
                         const float* __restrict__ fb1, const float* __restrict__ fb2,
                         const float* __restrict__ fb3,
                         unsigned short* nhwc, unsigned short* t1, unsigned short* t2,
                         unsigned short* corr, unsigned short* f1b, unsigned short* f2b,
                         unsigned short* d1, unsigned short* d2, unsigned short* d3,
                         unsigned short* d4, unsigned short* d5, unsigned short* d6,
                         float* __restrict__ aff) {
    int b = blockIdx.x;
    int tid = threadIdx.x;
    if (b < 16384) {
        // nhwc convert: NCHW fp32 [3][512][512] -> padded NHWC4 bf16 [518][518][4]
        int z = b >> 10;
        const float* src = (z < 8) ? cloth + (size_t)z * 786432
                                   : person + (size_t)(z - 8) * 786432;
        int p = (b & 1023) * 256 + tid;
        int row = p >> 9, col = p & 511;
        u16x4 o;
        o[0] = f2bf(src[p]);
        o[1] = f2bf(src[262144 + p]);
        o[2] = f2bf(src[524288 + p]);
        o[3] = 0;
        *(u16x4*)&nhwc[(size_t)z * 1073296 + ((size_t)(row + 3) * 518 + col + 3) * 4] = o;
    } else if (b < 18900) {
        // weight repack + BN fold (flattened)
        int idx = (b - 16384) * 256 + tid;
        if (idx < 16384) {        // conv1: [64,3,7,7] -> [64][256], k = kh*32 + kw*4 + ic
            int m = idx >> 8, k = idx & 255;
            int kh = k >> 5, r = k & 31, kw = r >> 2, ic = r & 3;
            unsigned short v = 0;
            if (kh < 7 && kw < 7 && ic < 3) v = f2bf(w1[((m * 3 + ic) * 7 + kh) * 7 + kw]);
            d1[idx] = v;
        } else if (idx < 90112)  wconv3x3(w2, d2, 128, 576, 64, 64, idx - 16384);
        else if (idx < 385024)   wconv3x3(w3, d3, 256, 1152, 128, 128, idx - 90112);
        else if (idx < 532480)   wconv3x3(fw1, d4, 128, 1152, 81, 128, idx - 385024);
        else if (idx < 606208)   wconv3x3(fw2, d5, 64, 1152, 128, 128, idx - 532480);
        else if (idx < 643072)   wconv3x3(fw3, d6, 2, 576, 64, 64, idx - 606208);
        else {                   // BN fold (642 channels)
            int i = idx - 643072;
            if (i < 64) {
                float s = g1[i] * rsqrtf(v1[i] + EPS);
                aff[i] = s; aff[64 + i] = (b1[i] - m1[i]) * s + be1[i];
            } else if (i < 192) {
                int c = i - 64; float s = g2[c] * rsqrtf(v2[c] + EPS);
                aff[128 + c] = s; aff[256 + c] = (b2[c] - m2[c]) * s + be2[c];
            } else if (i < 448) {
                int c = i - 192; float s = g3[c] * rsqrtf(v3[c] + EPS);
                aff[384 + c] = s; aff[640 + c] = (b3[c] - m3[c]) * s + be3[c];
            } else if (i < 576) {
                int c = i - 448; aff[896 + c] = 1.f; aff[1024 + c] = fb1[c];
            } else if (i < 640) {
                int c = i - 576; aff[1152 + c] = 1.f; aff[1216 + c] = fb2[c];
            } else if (i < 642) {
                int c = i - 640; aff[1280 + c] = 1.f; aff[1288 + c] = fb3[c];
            }
        }
    } else {
        // pad rings: role 0 nhwc 3-ring, 1 t1, 2 t2, 3 corr/f1b/f2b
        int bb = b - 18900;
        int role = bb / 516;
        int idx = (bb - role * 516) * 256 + tid;
        if (role == 0) {
            if (idx >= 16 * 6180) return;
            int z = idx / 6180, p = idx - z * 6180;
            int r, c;
            if (p < 1554) { r = p / 518; c = p - (p / 518) * 518; }
            else if (p < 3108) { int q = p - 1554; r = 515 + q / 518; c = q - (q / 518) * 518; }
            else { int q = p - 3108; r = 3 + q / 6; int k = q - (q / 6) * 6; c = (k < 3) ? k : 512 + k; }
            const u16x4 zv = {0, 0, 0, 0};
            *(u16x4*)&nhwc[(size_t)z * 1073296 + ((size_t)r * 518 + c) * 4] = zv;
        } else if (role == 1) {
            ring1_zero(t1, 258, 258, 8, 4260096, 16, idx);
        } else if (role == 2) {
            ring1_zero(t2, 130, 130, 16, 2163200, 16, idx);
        } else {
            if (idx < 33280) ring1_zero(corr, 66, 66, 16, 557568, 8, idx);
            else if (idx < 66560) ring1_zero(f1b, 66, 66, 16, 557568, 8, idx - 33280);
            else if (idx < 83200) ring1_zero(f2b, 66, 66, 8, 278784, 8, idx - 66560);
        }
    }
}

// ------- MFMA GEMM, implicit im2col, global_load_lds staging -------
// MODE 1: 3x3 conv pad1, X = padded NHWC [HIN+2][HIN+2][CIN], K layout tap*CIN+ic. KSTEP=64.
// MODE 2: conv1 7x7 s2 p3, X = padded NHWC4 [518][518][4], K layout kh*32+kw*4+ic.
//         KSTEP=64: round = 2 kh rows (NKT=4, K=256). KSTEP=32: round = 1 kh row (NKT=7, K=224,
//         skips all-zero kh=7 row; weight buffer stays [64][256]).
// PIPE 0: single LDS buffer, drain per round.  PIPE 1: dbuf + counted vmcnt.
template <int WR, int WS, int MODE, bool RELU, bool OUT_NCHW, int CIN, int NKT,
          int HIN, int WOS, int STRIDE, int OPAD, int PIPE, int KSTEP>
__global__ __launch_bounds__(WR * WS * 64)
void gemm_conv(const unsigned short* __restrict__ X, const unsigned short* __restrict__ Wmk,
               const float* __restrict__ scale, const float* __restrict__ shift,
               void* __restrict__ Yv, int Cout, int xImgStride, int yImgStride) {
    constexpr int BR = WR * 64, BS = WS * 64, NT = WR * WS * 64;
    constexpr int CPR_K = KSTEP / 8;                      // 16B chunks per LDS row
    constexpr int SXC = BR * CPR_K / NT, SWC = BS * CPR_K / NT;
    constexpr int NLOAD = SXC + SWC;
    constexpr int KP = (MODE == 1) ? NKT * KSTEP : 256;   // weight row stride
    constexpr int WP = HIN + ((MODE == 2) ? 6 : 2);       // padded width
    constexpr int WOUT = 1 << WOS;
    constexpr int WOP = WOUT + 2 * OPAD;
    constexpr int NBUF = PIPE ? 2 : 1;
    constexpr int EPS_LDK = BS + 8;                        // epilogue row stride
    constexpr int GEMM_ELEMS = NBUF * (BR + BS) * KSTEP;
    constexpr int EPI_ELEMS = BR * EPS_LDK;
    constexpr int LDS_ELEMS = GEMM_ELEMS > EPI_ELEMS ? GEMM_ELEMS : EPI_ELEMS;
    __shared__ __align__(16) unsigned short lds[LDS_ELEMS];
    unsigned short* XsB = lds;                       // [NBUF][BR*KSTEP]
    unsigned short* WsB = lds + NBUF * BR * KSTEP;   // [NBUF][BS*KSTEP]
    const int tid = threadIdx.x;
    const int lane = tid & 63, wid = tid >> 6;
    const int wr = wid % WR, wsx = wid / WR;
    int bx = blockIdx.x;
    { const int nx = gridDim.x; bx = (bx & 7) * (nx >> 3) + (bx >> 3); }  // XCD swizzle
    const int r0 = bx * BR, s0 = blockIdx.y * BS;
    const int z = blockIdx.z;
    const int lr = lane & 15, lk = lane >> 4;
    const unsigned short* Ximg = X + (size_t)z * xImgStride;

    // per-chunk global source base (kt=0); LDS slot p of row r holds K-chunk p^(r&(CPR_K-1))
    const unsigned short* xsrc[SXC];
    #pragma unroll
    for (int i = 0; i < SXC; ++i) {
        int c = i * NT + tid;
        int row = c / CPR_K, chs = (c % CPR_K) ^ (row & (CPR_K - 1));
        int r = r0 + row;
        int oh = r >> WOS, ow = r & (WOUT - 1);
        if (MODE == 1)
            xsrc[i] = Ximg + ((size_t)(oh * STRIDE) * WP + (size_t)(ow * STRIDE)) * CIN + chs * 8;
        else if (KSTEP == 64)
            xsrc[i] = Ximg + ((size_t)(2 * oh + (chs >> 2)) * WP + 2 * ow + (chs & 3) * 2) * 4;
        else  // MODE 2, KSTEP 32: chunk = kw pair {2chs, 2chs+1}, one kh row per round
            xsrc[i] = Ximg + ((size_t)(2 * oh) * WP + 2 * ow + chs * 2) * 4;
    }
    const unsigned short* wsrc[SWC];
    #pragma unroll
    for (int i = 0; i < SWC; ++i) {
        int c = i * NT + tid;
        int row = c / CPR_K, chs = (c % CPR_K) ^ (row & (CPR_K - 1));
        wsrc[i] = Wmk + (size_t)(s0 + row) * KP + chs * 8;
    }

    // fragment row bases
    int arow[4], brow[4];
    #pragma unroll
    for (int mi = 0; mi < 4; ++mi) arow[mi] = (wr * 64 + mi * 16 + lr) * KSTEP;
    #pragma unroll
    for (int si = 0; si < 4; ++si) brow[si] = (wsx * 64 + si * 16 + lr) * KSTEP;

    const f32x4 fz = {0.f, 0.f, 0.f, 0.f};
    f32x4 acc[4][4];
    #pragma unroll
    for (int a = 0; a < 4; ++a)
        #pragma unroll
        for (int b = 0; b < 4; ++b) acc[a][b] = fz;

    // stage round kt into LDS buffer b
    auto stage = [&](int kt, int b) {
        size_t koff;
        if (MODE == 1) {
            const int tap = (kt * KSTEP) / CIN;
            const int kh = tap / 3, kw = tap - (tap / 3) * 3;
            const int icb0 = (kt * KSTEP) % CIN;
            koff = ((size_t)kh * WP + kw) * CIN + icb0;
        } else if (KSTEP == 64) {
            koff = (size_t)kt * 2 * WP * 4;
        } else {
            koff = (size_t)kt * WP * 4;     // one kh row per round
        }
        #pragma unroll
        for (int i = 0; i < SXC; ++i)
            gload16(xsrc[i] + koff, &XsB[b * BR * KSTEP + (i * NT + wid * 64) * 8]);
        #pragma unroll
        for (int i = 0; i < SWC; ++i)
            gload16(wsrc[i] + (size_t)kt * KSTEP, &WsB[b * BS * KSTEP + (i * NT + wid * 64) * 8]);
    };
    // MFMA over buffer b
    auto compute = [&](int b) {
        if constexpr (KSTEP == 64) {
            #pragma unroll
            for (int hf = 0; hf < 2; ++hf) {
                const int cA = (((hf * 4 + lk) ^ (lr & 7)) * 8);
                u16x8 af[4], bfr[4];
                #pragma unroll
                for (int mi = 0; mi < 4; ++mi) af[mi] = *(const u16x8*)&XsB[b * BR * 64 + arow[mi] + cA];
                #pragma unroll
                for (int si = 0; si < 4; ++si) bfr[si] = *(const u16x8*)&WsB[b * BS * 64 + brow[si] + cA];
                #pragma unroll
                for (int mi = 0; mi < 4; ++mi)
                    #pragma unroll
                    for (int si = 0; si < 4; ++si)
                        acc[mi][si] = __builtin_amdgcn_mfma_f32_16x16x32_bf16(
                            __builtin_bit_cast(bf16x8_t, af[mi]),
                            __builtin_bit_cast(bf16x8_t, bfr[si]), acc[mi][si], 0, 0, 0);
            }
        } else {
            const int cA = ((lk ^ (lr & 3)) * 8);
            u16x8 af[4], bfr[4];
            #pragma unroll
            for (int mi = 0; mi < 4; ++mi) af[mi] = *(const u16x8*)&XsB[b * BR * 32 + arow[mi] + cA];
            #pragma unroll
            for (int si = 0; si < 4; ++si) bfr[si] = *(const u16x8*)&WsB[b * BS * 32 + brow[si] + cA];
            #pragma unroll
            for (int mi = 0; mi < 4; ++mi)
                #pragma unroll
                for (int si = 0; si < 4; ++si)
                    acc[mi][si] = __builtin_amdgcn_mfma_f32_16x16x32_bf16(
                        __builtin_bit_cast(bf16x8_t, af[mi]),
                        __builtin_bit_cast(bf16x8_t, bfr[si]), acc[mi][si], 0, 0, 0);
        }
    };

    if (PIPE == 0) {
        #pragma unroll
        for (int kt = 0; kt < NKT; ++kt) {
            stage(kt, 0);
            __syncthreads();
            compute(0);
            __syncthreads();
        }
    } else {
        stage(0, 0);
        #pragma unroll
        for (int kt = 0; kt < NKT; ++kt) {
            const int cur = kt & 1;
            if (kt + 1 < NKT) {
                stage(kt + 1, cur ^ 1);
                s_waitcnt_vm<NLOAD>();   // prev round's loads landed; new ones in flight
            } else {
                s_waitcnt_vm<0>();
            }
            __builtin_amdgcn_sched_barrier(0);
            __builtin_amdgcn_s_barrier();
            __builtin_amdgcn_sched_barrier(0);
            compute(cur);
            __builtin_amdgcn_sched_barrier(0);
            __builtin_amdgcn_s_barrier();   // reads of buf[cur] done before restage
        }
    }

    // ---- epilogue ----
    if (OUT_NCHW) {
        // fconv3: scalar fp32 NCHW stores (tiny)
        #pragma unroll
        for (int si = 0; si < 4; ++si) {
            int col = s0 + wsx * 64 + si * 16 + lr;
            bool cok = col < Cout;
            float sc = cok ? scale[col] : 0.f;
            float sh = cok ? shift[col] : 0.f;
            #pragma unroll
            for (int mi = 0; mi < 4; ++mi) {
                int rbase = r0 + wr * 64 + mi * 16 + lk * 4;
                #pragma unroll
                for (int j = 0; j < 4; ++j) {
                    float v = acc[mi][si][j] * sc + sh;
                    if (RELU) v = fmaxf(v, 0.f);
                    if (cok) ((float*)Yv)[(size_t)z * yImgStride + col * 4096 + rbase + j] = v;
                }
            }
        }
    } else {
        // stage bf16 tile in LDS (stride BS+8), then coalesced u16x8 stores
        __syncthreads();
        unsigned short* epi = lds;
        #pragma unroll
        for (int si = 0; si < 4; ++si) {
            int col = wsx * 64 + si * 16 + lr;
            float sc = scale[s0 + col];
            float sh = shift[s0 + col];
            #pragma unroll
            for (int mi = 0; mi < 4; ++mi) {
                int rowl = wr * 64 + mi * 16 + lk * 4;
                #pragma unroll
                for (int j = 0; j < 4; ++j) {
                    float v = acc[mi][si][j] * sc + sh;
                    if (RELU) v = fmaxf(v, 0.f);
                    epi[(rowl + j) * EPS_LDK + col] = f2bf(v);
                }
            }
        }
        __syncthreads();
        constexpr int NCH = BR * BS / 8 / NT;        // 8-col chunks per thread
        constexpr int CPR = BS / 8;                  // chunks per row
        #pragma unroll
        for (int i = 0; i < NCH; ++i) {
            int c = i * NT + tid;
            int row = c / CPR, colc = c - (c / CPR) * CPR;
            int r = r0 + row;
            int oh = r >> WOS, ow = r & (WOUT - 1);
            size_t off = ((size_t)(oh + OPAD) * WOP + ow + OPAD) * Cout + s0 + colc * 8;
            *(u16x8*)((unsigned short*)Yv + (size_t)z * yImgStride + off) =
                *(const u16x8*)&epi[row * EPS_LDK + colc * 8];
        }
    }
}

// ------- banded-MFMA 81-shift correlation, di split across grid for occupancy -------
__global__ __launch_bounds__(256)
void corr_mfma(const unsigned short* __restrict__ cf,
               const unsigned short* __restrict__ pf,
               unsigned short* __restrict__ out) {
    const int h = blockIdx.x;            // 0..63
    const int di = (int)blockIdx.y - 4;  // -4..4
    const int z = blockIdx.z;            // 0..7
    const int tid = threadIdx.x;
    const int lane = tid & 63, t = tid >> 6;
    const int lr = lane & 15, lk = lane >> 4;
    const unsigned short* cfi = cf + (size_t)z * 1048576;
    const unsigned short* pfi = pf + (size_t)z * 1048576;
    unsigned short* outp = out + (size_t)z * 557568;

    u16x8 a[8];
    {
        const unsigned short* ap = cfi + ((size_t)(h * 64 + t * 16 + lr)) * 256 + lk * 8;
        #pragma unroll
        for (int ks = 0; ks < 8; ++ks) a[ks] = *(const u16x8*)(ap + ks * 32);
    }

    const u16x8 zz = {0, 0, 0, 0, 0, 0, 0, 0};
    const int h2 = h + di;
    const bool hok = (unsigned)h2 < 64u;
    #pragma unroll
    for (int ct = 0; ct < 2; ++ct) {
        const int wpg = t * 16 - 8 + ct * 16 + lr;
        u16x8 b[8];
        if (hok && (unsigned)wpg < 64u) {
            const unsigned short* bp = pfi + ((size_t)(h2 * 64 + wpg)) * 256 + lk * 8;
            #pragma unroll
            for (int ks = 0; ks < 8; ++ks) b[ks] = *(const u16x8*)(bp + ks * 32);
        } else {
            #pragma unroll
            for (int ks = 0; ks < 8; ++ks) b[ks] = zz;
        }
        f32x4 acc0 = {0.f, 0.f, 0.f, 0.f}, acc1 = {0.f, 0.f, 0.f, 0.f};
        #pragma unroll
        for (int ks = 0; ks < 8; ks += 2) {
            acc0 = __builtin_amdgcn_mfma_f32_16x16x32_bf16(
                __builtin_bit_cast(bf16x8_t, a[ks]),
                __builtin_bit_cast(bf16x8_t, b[ks]), acc0, 0, 0, 0);
            acc1 = __builtin_amdgcn_mfma_f32_16x16x32_bf16(
                __builtin_bit_cast(bf16x8_t, a[ks + 1]),
                __builtin_bit_cast(bf16x8_t, b[ks + 1]), acc1, 0, 0, 0);
        }
        const int wl = lk * 4;
        const int wpl = ct * 16 - 8 + lr;
        #pragma unroll
        for (int j = 0; j < 4; ++j) {
            int dj = wpl - (wl + j);
            if (dj >= -4 && dj <= 4) {
                int s = (di + 4) * 9 + dj + 4;
                int w = t * 16 + wl + j;
                outp[((size_t)(h + 1) * 66 + w + 1) * 128 + s] =
                    f2bf(acc0[j] + acc1[j]);
            }
        }
    }
}

// ---------------- launch ----------------
extern "C" void kernel_launch(void* const* d_in, const int* in_sizes, int n_in,
                              void* d_out, int out_size, void* d_ws, size_t ws_size,
                              hipStream_t stream) {
    const float* cloth  = (const float*)d_in[0];
    const float* person = (const float*)d_in[1];
    const float* w1 = (const float*)d_in[2];  const float* b1 = (const float*)d_in[3];
    const float* g1 = (const float*)d_in[4];  const float* be1 = (const float*)d_in[5];
    const float* m1 = (const float*)d_in[6];  const float* v1 = (const float*)d_in[7];
    const float* w2 = (const float*)d_in[8];  const float* b2 = (const float*)d_in[9];
    const float* g2 = (const float*)d_in[10]; const float* be2 = (const float*)d_in[11];
    const float* m2 = (const float*)d_in[12]; const float* v2 = (const float*)d_in[13];
    const float* w3 = (const float*)d_in[14]; const float* b3 = (const float*)d_in[15];
    const float* g3 = (const float*)d_in[16]; const float* be3 = (const float*)d_in[17];
    const float* m3 = (const float*)d_in[18]; const float* v3 = (const float*)d_in[19];
    const float* fw1 = (const float*)d_in[20]; const float* fb1 = (const float*)d_in[21];
    const float* fw2 = (const float*)d_in[22]; const float* fb2 = (const float*)d_in[23];
    const float* fw3 = (const float*)d_in[24]; const float* fb3 = (const float*)d_in[25];

    char* ws = (char*)d_ws;
    auto U = [&](size_t off) { return (unsigned short*)(ws + off); };
    // ---- layout (bytes), ws_size = 256 MiB = 268,435,456 ----
    unsigned short* nhwc = U(0);             // [518][518][4] x16 = 34,345,472
    unsigned short* t1   = U(34345472);      // [258][258][64] x16 = 136,323,072 -> ends 170,668,544
    unsigned short* cf   = U(34345472);      // alias t1 (dead after conv2): [64][64][256] x16
    unsigned short* t2   = U(170668544);     // [130][130][128] x16 = 69,222,400 -> ends 239,890,944
    unsigned short* w1mk  = U(239890944);    //  32,768 (64x256)
    unsigned short* w2mk  = U(239923712);    // 147,456 (128x576)
    unsigned short* w3mk  = U(240071168);    // 589,824 (256x1152)
    unsigned short* fw1mk = U(240660992);    // 294,912 (128x1152)
    unsigned short* fw2mk = U(240955904);    // 147,456 (64x1152)
    unsigned short* fw3mk = U(241103360);    //  73,728 (64x576) -> ends 241,177,088
    float* aff = (float*)(ws + 241177088);   // 8 KB
    unsigned short* corr = U(241185280);     // [66][66][128] x8 = 8,921,088 -> ends 250,106,368
    unsigned short* f1b  = U(250106368);     // [66][66][128] x8 = 8,921,088 -> ends 259,027,456
    unsigned short* f2b  = U(259027456);     // [66][66][64]  x8 = 4,460,544 -> ends 263,488,000
    float *s1 = aff,         *sh1 = aff + 64,   *s2 = aff + 128,  *sh2 = aff + 256;
    float *s3 = aff + 384,   *sh3 = aff + 640,  *sf1 = aff + 896, *shf1 = aff + 1024;
    float *sf2 = aff + 1152, *shf2 = aff + 1216, *sf3 = aff + 1280, *shf3 = aff + 1288;

    // single fused prep launch: nhwc convert (16384 blk) + weights/affine (2516) + rings (2064)
    prep_all<<<20964, 256, 0, stream>>>(cloth, person, w1, w2, w3, fw1, fw2, fw3,
                                        b1, g1, be1, m1, v1, b2, g2, be2, m2, v2,
                                        b3, g3, be3, m3, v3, fb1, fb2, fb3,
                                        nhwc, t1, t2, corr, f1b, f2b,
                                        w1mk, w2mk, w3mk, fw1mk, fw2mk, fw3mk, aff);

    // conv1: 7x7 s2 p3, nhwc[518,518,4] -> t1 pad[258,258,64]
    // dbuf BK32, NKT=7 (K=224, zero kh=7 row skipped), 40 KB LDS -> 4 blk/CU + pipeline
    gemm_conv<4, 1, 2, true, false, 4, 7, 512, 8, 2, 1, 1, 32><<<dim3(256, 1, 16), 256, 0, stream>>>(
        nhwc, w1mk, s1, sh1, t1, 64, 1073296, 4260096);
    // conv2: 3x3 s2 p1, t1 -> t2 pad[130,130,128]   (dbuf BK64, R13-proven)
    gemm_conv<2, 2, 1, true, false, 64, 9, 256, 7, 2, 1, 1, 64><<<dim3(128, 1, 16), 256, 0, stream>>>(
        t1, w2mk, s2, sh2, t2, 128, 4260096, 2163200);
    // conv3: 3x3 s2 p1, t2 -> cf/pf unpadded [64,64,256]   (dbuf BK64, R13-proven)
    gemm_conv<2, 2, 1, true, false, 128, 18, 128, 6, 2, 0, 1, 64><<<dim3(32, 2, 16), 256, 0, stream>>>(
        t2, w3mk, s3, sh3, cf, 256, 2163200, 1048576);

    // correlation (banded MFMA, di-split grid) -> corr pad[66,66,128]
    corr_mfma<<<dim3(64, 9, 8), 256, 0, stream>>>(cf, cf + (size_t)8 * 1048576, corr);

    // fconv1: 3x3 p1, corr -> f1b pad[66,66,128]   (dbuf BK64, BR=64 tile)
    gemm_conv<1, 2, 1, true, false, 128, 18, 64, 6, 1, 1, 1, 64><<<dim3(64, 1, 8), 128, 0, stream>>>(
        corr, fw1mk, sf1, shf1, f1b, 128, 557568, 557568);
    // fconv2: 3x3 p1, f1b -> f2b pad[66,66,64]   (dbuf BK64)
    gemm_conv<2, 1, 1, true, false, 128, 18, 64, 6, 1, 1, 1, 64><<<dim3(32, 1, 8), 128, 0, stream>>>(
        f1b, fw2mk, sf2, shf2, f2b, 64, 557568, 278784);
    // fconv3: 3x3 p1, f2b -> d_out NCHW fp32 [8][2][64][64]   (dbuf BK64)
    gemm_conv<2, 1, 1, false, true, 64, 9, 64, 6, 1, 0, 1, 64><<<dim3(32, 1, 8), 128, 0, stream>>>(
        f2b, fw3mk, sf3, shf3, (float*)d_out, 2, 278784, 8192);
}